// Round 11
// baseline (237.295 us; speedup 1.0000x reference)
//
#include <hip/hip_runtime.h>
#include <math.h>
#include <float.h>

constexpr int NE   = 64;     // experts
constexpr int ND   = 2048;   // hidden dim
constexpr int TOPK = 8;
constexpr int TOKS = 64;     // tokens per block (= lanes)
constexpr int NWV  = 16;     // waves per block
constexpr int G    = NE / NWV; // 4 experts per thread

// Emulates the np gold: h @ w.T via OpenBLAS sgemm (fp32) semantics.
// K=2048 -> kc panels {384,384,384,384,256,256} (SGEMM_Q=384, tail halving).
// Per C-element, per panel: ONE accumulator, serial fp32 FMA, k ascending
// (vfmadd231ps chain). Panel results added to C in fp32, in order.
// Then np ufuncs: l = fadd(fmul(raw, cs), cb) (fp32, unfused).
// Rank on l32; ties -> lower index (stable argsort). Softmax values fp32.
__global__ __launch_bounds__(NWV * 64, 1)
void gate_kernel(const float* __restrict__ h, const float* __restrict__ w,
                 const float* __restrict__ cs, const float* __restrict__ cb,
                 float* __restrict__ out, int T)
{
    __shared__ float sl[NE * TOKS];   // l32 logits [e][t], 16 KB
    __shared__ float pp[TOKS * NE];   // [t][e] swizzled unnormalized probs, 16 KB
    __shared__ float pinv[TOKS];

    const int tid  = threadIdx.x;
    const int lane = tid & 63;
    const int wv   = __builtin_amdgcn_readfirstlane(tid >> 6);
    const int tok  = blockIdx.x * TOKS + lane;
    const int e0   = wv * G;

    float C[G];
#pragma unroll
    for (int g = 0; g < G; ++g) C[g] = 0.f;

    const float* hrow = h + (size_t)tok * ND;

    int k = 0;
#pragma unroll 1
    for (int p = 0; p < 6; ++p) {
        const int kend = (p < 4) ? (p + 1) * 384 : (1536 + (p - 3) * 256);

        float a[G];
#pragma unroll
        for (int g = 0; g < G; ++g) a[g] = 0.f;

#pragma unroll 1
        for (; k < kend; k += 8) {
            const float4 hv0 = *reinterpret_cast<const float4*>(hrow + k);
            const float4 hv1 = *reinterpret_cast<const float4*>(hrow + k + 4);

#pragma unroll
            for (int g = 0; g < G; ++g) {
                const float* wp = w + (size_t)(e0 + g) * ND + k; // wave-uniform -> s_load
                const float w0 = wp[0], w1 = wp[1], w2 = wp[2], w3 = wp[3];
                const float w4 = wp[4], w5 = wp[5], w6 = wp[6], w7 = wp[7];
                // serial fp32 FMA, strictly ascending k (BLAS micro-kernel chain)
                float t0 = a[g];
                t0 = __builtin_fmaf(hv0.x, w0, t0);
                t0 = __builtin_fmaf(hv0.y, w1, t0);
                t0 = __builtin_fmaf(hv0.z, w2, t0);
                t0 = __builtin_fmaf(hv0.w, w3, t0);
                t0 = __builtin_fmaf(hv1.x, w4, t0);
                t0 = __builtin_fmaf(hv1.y, w5, t0);
                t0 = __builtin_fmaf(hv1.z, w6, t0);
                t0 = __builtin_fmaf(hv1.w, w7, t0);
                a[g] = t0;
            }
        }

        // panel result added to C in fp32 (first panel: 0 + a, exact)
#pragma unroll
        for (int g = 0; g < G; ++g) C[g] = __fadd_rn(C[g], a[g]);
    }

    // np ufuncs: mul then add, both rounded fp32, no fma contraction
#pragma unroll
    for (int g = 0; g < G; ++g) {
        const int e = e0 + g;
        sl[e * TOKS + lane] = __fadd_rn(__fmul_rn(C[g], cs[e]), cb[e]);
    }
    __syncthreads();

    float* const out_probs = out;                           // T*64
    float* const out_wts   = out + (size_t)T * NE;          // T*8
    float* const out_idx   = out + (size_t)T * (NE + TOPK); // T*8

    if (wv == 0) {
        float l[NE];
#pragma unroll
        for (int e = 0; e < NE; ++e) l[e] = sl[e * TOKS + lane];

        float m = l[0];
#pragma unroll
        for (int e = 1; e < NE; ++e) m = fmaxf(m, l[e]);

        float u[NE];
        float s = 0.f;
#pragma unroll
        for (int e = 0; e < NE; ++e) {
            u[e] = expf(l[e] - m);
            s += u[e];
        }
        const float inv = 1.f / s;
        pinv[lane] = inv;

        // stage unnormalized probs, XOR-swizzled (conflict-free)
#pragma unroll
        for (int e = 0; e < NE; ++e)
            pp[lane * NE + (e ^ (lane & 31))] = u[e];

        // top-8 on l32; strict > insertion, e ascending => ties keep lower index
        float kv[TOPK]; int iv[TOPK];
#pragma unroll
        for (int j = 0; j < TOPK; ++j) { kv[j] = -FLT_MAX; iv[j] = 0; }
#pragma unroll
        for (int e = 0; e < NE; ++e) {
            float v = l[e]; int ix = e;
#pragma unroll
            for (int j = 0; j < TOPK; ++j) {
                const bool gt = v > kv[j];
                const float nv = gt ? kv[j] : v;
                const int   ni = gt ? iv[j] : ix;
                kv[j] = gt ? v  : kv[j];
                iv[j] = gt ? ix : iv[j];
                v = nv; ix = ni;
            }
        }

        float ws0[TOPK];
#pragma unroll
        for (int j = 0; j < TOPK; ++j)
            ws0[j] = pp[lane * NE + (iv[j] ^ (lane & 31))] * inv;

        *reinterpret_cast<float4*>(out_wts + (size_t)tok * TOPK)
            = make_float4(ws0[0], ws0[1], ws0[2], ws0[3]);
        *reinterpret_cast<float4*>(out_wts + (size_t)tok * TOPK + 4)
            = make_float4(ws0[4], ws0[5], ws0[6], ws0[7]);
        *reinterpret_cast<float4*>(out_idx + (size_t)tok * TOPK)
            = make_float4((float)iv[0], (float)iv[1], (float)iv[2], (float)iv[3]);
        *reinterpret_cast<float4*>(out_idx + (size_t)tok * TOPK + 4)
            = make_float4((float)iv[4], (float)iv[5], (float)iv[6], (float)iv[7]);
    }
    __syncthreads();

    // cooperative coalesced probs store: 4096 floats / 1024 threads = 4 each
    {
        const size_t base = (size_t)blockIdx.x * TOKS * NE;
#pragma unroll
        for (int r = 0; r < (TOKS * NE) / (NWV * 64); ++r) {
            const int idx = r * (NWV * 64) + tid;
            const int t = idx >> 6, e = idx & 63;
            out_probs[base + idx] = pp[t * NE + (e ^ (t & 31))] * pinv[t];
        }
    }
}

extern "C" void kernel_launch(void* const* d_in, const int* in_sizes, int n_in,
                              void* d_out, int out_size, void* d_ws, size_t ws_size,
                              hipStream_t stream)
{
    const float* h  = (const float*)d_in[0];
    const float* w  = (const float*)d_in[1];
    const float* cs = (const float*)d_in[2];
    const float* cb = (const float*)d_in[3];
    float* outp = (float*)d_out;
    const int T = in_sizes[0] / ND;   // 16384 tokens

    dim3 grid(T / TOKS);              // 256 blocks
    dim3 block(NWV * 64);             // 1024 threads
    hipLaunchKernelGGL(gate_kernel, grid, block, 0, stream,
                       h, w, cs, cb, outp, T);
}